// Round 3
// baseline (1656.309 us; speedup 1.0000x reference)
//
#include <hip/hip_runtime.h>
#include <math.h>

// SO3 DiT layer, MI355X.
// Round 3: attention split into streaming Pass A (eq/ev GEMM + logits) and
// gather Pass B (block-per-dst online softmax, LDS merge). bf16 staging for
// q/k/v/ev/attn/logits. float4 broadcast loads everywhere (was scalar).

#define NN 6000
#define EE 72000

typedef unsigned short ushort_t;

__device__ __forceinline__ float wsum(float v) {
#pragma unroll
  for (int o = 32; o >= 1; o >>= 1) v += __shfl_xor(v, o, 64);
  return v;
}
__device__ __forceinline__ int deg_of(int m) { return (m == 0) ? 0 : ((m < 4) ? 1 : 2); }
__device__ __forceinline__ ushort_t f2b(float x) {
  unsigned u = __float_as_uint(x);
  unsigned r = ((u >> 16) & 1u) + 0x7fffu;
  return (ushort_t)((u + r) >> 16);
}
__device__ __forceinline__ float b2f(ushort_t h) {
  return __uint_as_float(((unsigned)h) << 16);
}

// ---------------- K1a: LayerNorm(T=64) + SiLU, one wave per node ----------------
__global__ __launch_bounds__(256) void k_ln_t(const float* __restrict__ ft,
                                              const float* __restrict__ lns,
                                              const float* __restrict__ lnb,
                                              float* __restrict__ sbuf) {
  int w = (blockIdx.x * 256 + threadIdx.x) >> 6;
  int lane = threadIdx.x & 63;
  float t = ft[(size_t)w * 64 + lane];
  float mu = wsum(t) * (1.f / 64.f);
  float d = t - mu;
  float var = wsum(d * d) * (1.f / 64.f);
  float cin = d * rsqrtf(var + 1e-6f) * lns[lane] + lnb[lane];
  sbuf[(size_t)w * 64 + lane] = cin / (1.f + expf(-cin));
}

// ---------------- K1b: c = silu @ W_c + b_c  (64 -> 1664), 8 nodes/block ----------------
__global__ __launch_bounds__(256) void k_cond_mm(const float* __restrict__ sbuf,
                                                 const float* __restrict__ Wc,
                                                 const float* __restrict__ bc,
                                                 float* __restrict__ c) {
  int n0 = blockIdx.x * 8;  // 750 blocks
  const float4* s4 = (const float4*)(sbuf + (size_t)n0 * 64);  // [nd*16 + t]
  for (int jj = threadIdx.x; jj < 1664; jj += 256) {
    float acc[8] = {0, 0, 0, 0, 0, 0, 0, 0};
#pragma unroll
    for (int t = 0; t < 16; t++) {
      float w0 = Wc[(size_t)(4 * t + 0) * 1664 + jj];
      float w1 = Wc[(size_t)(4 * t + 1) * 1664 + jj];
      float w2 = Wc[(size_t)(4 * t + 2) * 1664 + jj];
      float w3 = Wc[(size_t)(4 * t + 3) * 1664 + jj];
#pragma unroll
      for (int nd = 0; nd < 8; nd++) {
        float4 sv = s4[nd * 16 + t];
        acc[nd] += sv.x * w0 + sv.y * w1 + sv.z * w2 + sv.w * w3;
      }
    }
    float b = bc[jj];
#pragma unroll
    for (int nd = 0; nd < 8; nd++) c[(size_t)(n0 + nd) * 1664 + jj] = acc[nd] + b;
  }
}

// ---------------- K2/K8: eqv layernorm + modulate, one wave per (n,p) ----------------
__global__ __launch_bounds__(256) void k_lnmod(const float* __restrict__ xin,
                                               const float* __restrict__ c,
                                               float* __restrict__ xout,
                                               int goff, int boff) {
  int w = (blockIdx.x * 256 + threadIdx.x) >> 6;
  int lane = threadIdx.x & 63;
  int n = w >> 1, p = w & 1;
  const float* xb = xin + (size_t)w * 576 + lane;
  float x0 = xb[0], x1 = xb[64], x2 = xb[128], x3 = xb[192], x4 = xb[256];
  float x5 = xb[320], x6 = xb[384], x7 = xb[448], x8 = xb[512];
  float mu = wsum(x0) * (1.f / 64.f);
  x0 -= mu;
  float n20 = x0 * x0;
  float n21 = (x1 * x1 + x2 * x2 + x3 * x3) * (1.f / 3.f);
  float n22 = (x4 * x4 + x5 * x5 + x6 * x6 + x7 * x7 + x8 * x8) * (1.f / 5.f);
  n20 = wsum(n20) * (1.f / 64.f);
  n21 = wsum(n21) * (1.f / 64.f);
  n22 = wsum(n22) * (1.f / 64.f);
  float i0 = rsqrtf(n20 + 1e-6f), i1 = rsqrtf(n21 + 1e-6f), i2 = rsqrtf(n22 + 1e-6f);
  const float* cb = c + (size_t)n * 1664;
  float g0 = 1.f + cb[goff + p * 192 + lane];
  float g1 = 1.f + cb[goff + p * 192 + 64 + lane];
  float g2 = 1.f + cb[goff + p * 192 + 128 + lane];
  float bsh = cb[boff + lane];
  float* ob = xout + (size_t)w * 576 + lane;
  ob[0] = x0 * i0 * g0 + bsh;
  ob[64] = x1 * i1 * g1;
  ob[128] = x2 * i1 * g1;
  ob[192] = x3 * i1 * g1;
  ob[256] = x4 * i2 * g2;
  ob[320] = x5 * i2 * g2;
  ob[384] = x6 * i2 * g2;
  ob[448] = x7 * i2 * g2;
  ob[512] = x8 * i2 * g2;
}

// ---------------- K3: per-(p,m) 64x64 projection -> bf16 out ----------------
__global__ __launch_bounds__(256) void k_rowmat(const float* __restrict__ x,
                                                const float* __restrict__ W,
                                                ushort_t* __restrict__ outb) {
  int pm = blockIdx.y;
  int p = pm / 9, mm = pm % 9, dm = deg_of(mm);
  int lane = threadIdx.x & 63;
  const float* Wb = W + (size_t)(p * 3 + dm) * 4096;
  float wreg[64];
#pragma unroll
  for (int f = 0; f < 64; f++) wreg[f] = Wb[f * 64 + lane];
  int wid = (blockIdx.x * 256 + threadIdx.x) >> 6;
  int nwaves = (gridDim.x * 256) >> 6;
  for (int n = wid; n < NN; n += nwaves) {
    const float4* xr4 = (const float4*)(x + ((size_t)n * 18 + pm) * 64);
    float acc = 0.f;
#pragma unroll
    for (int t = 0; t < 16; t++) {
      float4 xv = xr4[t];
      acc += xv.x * wreg[4 * t] + xv.y * wreg[4 * t + 1] + xv.z * wreg[4 * t + 2] +
             xv.w * wreg[4 * t + 3];
    }
    outb[((size_t)n * 18 + pm) * 64 + lane] = f2b(acc);
  }
}

// ---------------- CSR build: histogram -> scan -> scatter ----------------
__global__ __launch_bounds__(256) void k_hist(const int* __restrict__ dst_idx,
                                              int* __restrict__ deg) {
  int e = blockIdx.x * 256 + threadIdx.x;
  if (e < EE) atomicAdd(deg + dst_idx[e], 1);
}

__global__ __launch_bounds__(1024) void k_scan(const int* __restrict__ deg,
                                               int* __restrict__ row_ptr,
                                               int* __restrict__ wptr) {
  __shared__ int part[1024];
  int t = threadIdx.x;
  int base = t * 6;
  int loc[6];
  int s = 0;
#pragma unroll
  for (int i = 0; i < 6; i++) {
    int idx = base + i;
    int d = (idx < NN) ? deg[idx] : 0;
    loc[i] = s;
    s += d;
  }
  part[t] = s;
  __syncthreads();
  int val = s;
  for (int off = 1; off < 1024; off <<= 1) {
    int tmp = (t >= off) ? part[t - off] : 0;
    __syncthreads();
    part[t] += tmp;
    __syncthreads();
  }
  int excl = part[t] - val;
#pragma unroll
  for (int i = 0; i < 6; i++) {
    int idx = base + i;
    if (idx < NN) {
      int v = excl + loc[i];
      row_ptr[idx] = v;
      wptr[idx] = v;
    }
  }
  if (t == 1023) row_ptr[NN] = excl + val;
}

__global__ __launch_bounds__(256) void k_scatter(const int* __restrict__ src_idx,
                                                 const int* __restrict__ dst_idx,
                                                 int* __restrict__ wptr,
                                                 int* __restrict__ csr_e,
                                                 int* __restrict__ csr_src) {
  int e = blockIdx.x * 256 + threadIdx.x;
  if (e < EE) {
    int d = dst_idx[e];
    int pos = atomicAdd(wptr + d, 1);
    csr_e[pos] = e;
    csr_src[pos] = src_idx[e];
  }
}

// ---------------- Pass A: edge-streaming eq/ev GEMM + logits ----------------
// Wave per edge. Weights (2x64 cols) in VGPRs; fe rows via float4 broadcast.
// Writes ev (bf16, [E][9][64]) and logits (bf16, [E][4]).
__global__ __launch_bounds__(256) void k_edge(const float* __restrict__ fe,
                                              const float* __restrict__ Weqk,
                                              const float* __restrict__ Wev,
                                              const ushort_t* __restrict__ qb,
                                              const ushort_t* __restrict__ kb,
                                              const int* __restrict__ src_idx,
                                              const int* __restrict__ dst_idx,
                                              ushort_t* __restrict__ evb,
                                              ushort_t* __restrict__ logb) {
  int lane = threadIdx.x & 63;
  float wqk[64], wev[64];
#pragma unroll
  for (int f = 0; f < 64; f++) {
    wqk[f] = Weqk[f * 64 + lane];
    wev[f] = Wev[f * 64 + lane];
  }
  int wid = (blockIdx.x * 256 + threadIdx.x) >> 6;
  int nw = (gridDim.x * 256) >> 6;
  for (int e = wid; e < EE; e += nw) {
    int s = src_idx[e];
    int d = dst_idx[e];
    const float4* fe4 = (const float4*)(fe + (size_t)e * 576);
    const ushort_t* qr = qb + (size_t)d * 1152 + lane;
    const ushort_t* kr = kb + (size_t)s * 1152 + lane;
    ushort_t* evr = evb + (size_t)e * 576 + lane;
    float lacc = 0.f;
#pragma unroll
    for (int m = 0; m < 9; m++) {
      float eq = 0.f, ev = 0.f;
#pragma unroll
      for (int t = 0; t < 16; t++) {
        float4 fv = fe4[m * 16 + t];
        eq += fv.x * wqk[4 * t] + fv.y * wqk[4 * t + 1] + fv.z * wqk[4 * t + 2] +
              fv.w * wqk[4 * t + 3];
        ev += fv.x * wev[4 * t] + fv.y * wev[4 * t + 1] + fv.z * wev[4 * t + 2] +
              fv.w * wev[4 * t + 3];
      }
      evr[m * 64] = f2b(ev);
      float q0 = b2f(qr[m * 64]), q1 = b2f(qr[m * 64 + 576]);
      float k0 = b2f(kr[m * 64]), k1 = b2f(kr[m * 64 + 576]);
      lacc += eq * (q0 * k0 + q1 * k1);
    }
    lacc *= 0.05892556509887896f;  // 1/sqrt(288)
    lacc += __shfl_xor(lacc, 8, 64);
    lacc += __shfl_xor(lacc, 4, 64);
    lacc += __shfl_xor(lacc, 2, 64);
    lacc += __shfl_xor(lacc, 1, 64);
    if ((lane & 15) == 0) logb[(size_t)e * 4 + (lane >> 4)] = f2b(lacc);
  }
}

// ---------------- Pass B: block-per-dst gather, online softmax, LDS merge ----------------
__global__ __launch_bounds__(256) void k_attnB(const ushort_t* __restrict__ evb,
                                               const ushort_t* __restrict__ vb,
                                               const ushort_t* __restrict__ logb,
                                               const float* __restrict__ cutoff,
                                               const int* __restrict__ row_ptr,
                                               const int* __restrict__ csr_e,
                                               const int* __restrict__ csr_src,
                                               ushort_t* __restrict__ attnb,
                                               float* __restrict__ meancut) {
  __shared__ float st[4][64][21];
  int d = blockIdx.x;
  int w = threadIdx.x >> 6, lane = threadIdx.x & 63;
  int beg = row_ptr[d], end = row_ptr[d + 1];
  float ml = -3.0e38f, dl = 0.f, cs = 0.f;
  float acc[18];
#pragma unroll
  for (int j = 0; j < 18; j++) acc[j] = 0.f;
  for (int i = beg + w; i < end; i += 4) {
    int e = csr_e[i];
    int s = csr_src[i];
    float lg = b2f(logb[(size_t)e * 4 + (lane >> 4)]);
    float co = cutoff[e];
    cs += co;
    float mnew = fmaxf(ml, lg);
    float sc = expf(ml - mnew);
    float wv = expf(lg - mnew) * co;
    dl = dl * sc + wv;
    const ushort_t* evr = evb + (size_t)e * 576 + lane;
    const ushort_t* vr = vb + (size_t)s * 1152 + lane;
#pragma unroll
    for (int m = 0; m < 9; m++) {
      float sv = wv * b2f(evr[m * 64]);
      acc[m] = acc[m] * sc + sv * b2f(vr[m * 64]);
      acc[m + 9] = acc[m + 9] * sc + sv * b2f(vr[m * 64 + 576]);
    }
    ml = mnew;
  }
  st[w][lane][0] = ml;
  st[w][lane][1] = dl;
  st[w][lane][2] = cs;
#pragma unroll
  for (int j = 0; j < 18; j++) st[w][lane][3 + j] = acc[j];
  __syncthreads();
  if (threadIdx.x < 64) {
    float M = st[0][lane][0];
#pragma unroll
    for (int w2 = 1; w2 < 4; w2++) M = fmaxf(M, st[w2][lane][0]);
    float D = 0.f, CS = 0.f;
    float A[18];
#pragma unroll
    for (int j = 0; j < 18; j++) A[j] = 0.f;
#pragma unroll
    for (int w2 = 0; w2 < 4; w2++) {
      float sc = expf(st[w2][lane][0] - M);
      D += st[w2][lane][1] * sc;
      CS += st[w2][lane][2];
#pragma unroll
      for (int j = 0; j < 18; j++) A[j] += st[w2][lane][3 + j] * sc;
    }
    float inv = 1.f / (D + 1e-9f);
    ushort_t* ob = attnb + (size_t)d * 1152 + lane;
#pragma unroll
    for (int m = 0; m < 9; m++) {
      ob[m * 64] = f2b(A[m] * inv);
      ob[m * 64 + 576] = f2b(A[m + 9] * inv);
    }
    if (lane == 0) meancut[d] = CS / fmaxf((float)(end - beg), 1.f);
  }
}

// ---------------- K7: Wo projection + post-select + gate(a1) + residual ----------------
__global__ __launch_bounds__(256) void k_wo_post(const ushort_t* __restrict__ attnb,
                                                 const float* __restrict__ Wo,
                                                 const float* __restrict__ xpre,
                                                 const float* __restrict__ fnodes,
                                                 const float* __restrict__ c,
                                                 const float* __restrict__ meancut,
                                                 float* __restrict__ out) {
  int pm = blockIdx.y;
  int p = pm / 9, mm = pm % 9, dm = deg_of(mm);
  int lane = threadIdx.x & 63;
  const float* Wb = Wo + (size_t)(p * 3 + dm) * 4096;
  float wreg[64];
#pragma unroll
  for (int f = 0; f < 64; f++) wreg[f] = Wb[f * 64 + lane];
  int wid = (blockIdx.x * 256 + threadIdx.x) >> 6;
  int nwaves = (gridDim.x * 256) >> 6;
  for (int n = wid; n < NN; n += nwaves) {
    const uint4* xr4 = (const uint4*)(attnb + ((size_t)n * 18 + pm) * 64);
    float acc = 0.f;
#pragma unroll
    for (int t = 0; t < 8; t++) {
      uint4 u = xr4[t];
      acc += __uint_as_float(u.x << 16) * wreg[8 * t + 0];
      acc += __uint_as_float(u.x & 0xffff0000u) * wreg[8 * t + 1];
      acc += __uint_as_float(u.y << 16) * wreg[8 * t + 2];
      acc += __uint_as_float(u.y & 0xffff0000u) * wreg[8 * t + 3];
      acc += __uint_as_float(u.z << 16) * wreg[8 * t + 4];
      acc += __uint_as_float(u.z & 0xffff0000u) * wreg[8 * t + 5];
      acc += __uint_as_float(u.w << 16) * wreg[8 * t + 6];
      acc += __uint_as_float(u.w & 0xffff0000u) * wreg[8 * t + 7];
    }
    float mc = meancut[n];
    size_t idx = ((size_t)n * 18 + pm) * 64 + lane;
    float post = (mc < 1e-5f) ? xpre[idx] : acc;
    float a1v = c[(size_t)n * 1664 + 448 + (p * 3 + dm) * 64 + lane];
    out[idx] = fnodes[idx] + a1v * post;
  }
}

// ---------------- K9a: h = eqv_gelu(x_pre2 @ W1), 8 nodes/block ----------------
__global__ __launch_bounds__(256) void k_mlp1(const float* __restrict__ xp2,
                                              const float* __restrict__ W1,
                                              float* __restrict__ h) {
  int n0 = blockIdx.x * 8;  // 750 blocks
  int j = threadIdx.x;
  float gate[8];
  {
    float acc[8] = {0, 0, 0, 0, 0, 0, 0, 0};
#pragma unroll
    for (int t = 0; t < 16; t++) {
      float w0 = W1[(size_t)(4 * t + 0) * 256 + j];
      float w1 = W1[(size_t)(4 * t + 1) * 256 + j];
      float w2 = W1[(size_t)(4 * t + 2) * 256 + j];
      float w3 = W1[(size_t)(4 * t + 3) * 256 + j];
#pragma unroll
      for (int nd = 0; nd < 8; nd++) {
        float4 xv = *(const float4*)(xp2 + (size_t)(n0 + nd) * 1152 + 4 * t);
        acc[nd] += xv.x * w0 + xv.y * w1 + xv.z * w2 + xv.w * w3;
      }
    }
#pragma unroll
    for (int nd = 0; nd < 8; nd++) {
      float s = acc[nd];
      float g = (fabsf(s) > 1e-4f)
                    ? 0.5f * (1.f + tanhf(0.7978845608028654f * (s + 0.044715f * s * s * s)))
                    : 0.5f;
      gate[nd] = g;
      h[(size_t)(n0 + nd) * 4608 + j] = s * g;
    }
  }
  for (int pm = 1; pm < 18; pm++) {
    int p = pm / 9, mm = pm % 9, dm = deg_of(mm);
    const float* wb = W1 + (size_t)(p * 3 + dm) * 16384;
    float acc[8] = {0, 0, 0, 0, 0, 0, 0, 0};
#pragma unroll
    for (int t = 0; t < 16; t++) {
      float w0 = wb[(size_t)(4 * t + 0) * 256 + j];
      float w1 = wb[(size_t)(4 * t + 1) * 256 + j];
      float w2 = wb[(size_t)(4 * t + 2) * 256 + j];
      float w3 = wb[(size_t)(4 * t + 3) * 256 + j];
#pragma unroll
      for (int nd = 0; nd < 8; nd++) {
        float4 xv = *(const float4*)(xp2 + (size_t)(n0 + nd) * 1152 + pm * 64 + 4 * t);
        acc[nd] += xv.x * w0 + xv.y * w1 + xv.z * w2 + xv.w * w3;
      }
    }
#pragma unroll
    for (int nd = 0; nd < 8; nd++)
      h[(size_t)(n0 + nd) * 4608 + pm * 256 + j] = acc[nd] * gate[nd];
  }
}

// ---------------- K9b: out += a2 * (h @ W2), 8 nodes/block ----------------
__global__ __launch_bounds__(256) void k_mlp2(const float* __restrict__ h,
                                              const float* __restrict__ W2,
                                              const float* __restrict__ c,
                                              float* __restrict__ out) {
  int n0 = blockIdx.x * 8;  // 750 blocks
  int g = threadIdx.x & 63;
  int pr = threadIdx.x >> 6;
  for (int pm = pr; pm < 18; pm += 4) {
    int p = pm / 9, mm = pm % 9, dm = deg_of(mm);
    const float* wb = W2 + (size_t)(p * 3 + dm) * 16384;
    float acc[8] = {0, 0, 0, 0, 0, 0, 0, 0};
#pragma unroll 16
    for (int t = 0; t < 64; t++) {
      float w0 = wb[(size_t)(4 * t + 0) * 64 + g];
      float w1 = wb[(size_t)(4 * t + 1) * 64 + g];
      float w2 = wb[(size_t)(4 * t + 2) * 64 + g];
      float w3 = wb[(size_t)(4 * t + 3) * 64 + g];
#pragma unroll
      for (int nd = 0; nd < 8; nd++) {
        float4 hv = *(const float4*)(h + (size_t)(n0 + nd) * 4608 + pm * 256 + 4 * t);
        acc[nd] += hv.x * w0 + hv.y * w1 + hv.z * w2 + hv.w * w3;
      }
    }
#pragma unroll
    for (int nd = 0; nd < 8; nd++) {
      int n = n0 + nd;
      size_t idx = ((size_t)n * 18 + pm) * 64 + g;
      out[idx] += c[(size_t)n * 1664 + 1280 + (p * 3 + dm) * 64 + g] * acc[nd];
    }
  }
}

// ---------------- workspace layout (bytes) ----------------
#define OFF_C 0UL             // f32 39,936,000
#define OFF_XPRE 39936000UL   // f32 27,648,000 (x_pre then x_pre2)
#define OFF_Q 67584000UL      // bf16 13,824,000
#define OFF_K 81408000UL      // bf16 13,824,000
#define OFF_V 95232000UL      // bf16 13,824,000
#define OFF_ATTN 109056000UL  // bf16 13,824,000
#define OFF_EV 122880000UL    // bf16 82,944,000 -> 205,824,000
#define OFF_SBUF 122880000UL  // f32 1,536,000 (overlays EV; dead before Pass A)
#define OFF_H 67584000UL      // f32 110,592,000 (overlays Q..EV head; after wo_post)
#define OFF_LOG 205824000UL   // bf16 576,000
#define OFF_DEG 206400000UL   // 24,000
#define OFF_ROWPTR 206424000UL // 24,032 (incl pad)
#define OFF_WPTR 206448032UL  // 24,000
#define OFF_CSRE 206472032UL  // 288,000
#define OFF_CSRSRC 206760032UL // 288,000
#define OFF_MEANCUT 207048032UL // 24,000
#define WS_NEEDED 207072032UL  // <= 207,216,000 proven available in round 1

extern "C" void kernel_launch(void* const* d_in, const int* in_sizes, int n_in,
                              void* d_out, int out_size, void* d_ws, size_t ws_size,
                              hipStream_t stream) {
  const float* f_nodes = (const float*)d_in[0];
  const float* f_edges = (const float*)d_in[1];
  const float* f_time = (const float*)d_in[2];
  const float* cutoff = (const float*)d_in[3];
  const float* ln_s = (const float*)d_in[4];
  const float* ln_b = (const float*)d_in[5];
  const float* W_c = (const float*)d_in[6];
  const float* b_c = (const float*)d_in[7];
  const float* Wq = (const float*)d_in[8];
  const float* Wk = (const float*)d_in[9];
  const float* Wv = (const float*)d_in[10];
  const float* Wo = (const float*)d_in[11];
  const float* We_qk = (const float*)d_in[12];
  const float* We_v = (const float*)d_in[13];
  const float* W1 = (const float*)d_in[14];
  const float* W2 = (const float*)d_in[15];
  const int* src_idx = (const int*)d_in[16];
  const int* dst_idx = (const int*)d_in[17];
  float* out = (float*)d_out;
  char* ws = (char*)d_ws;
  if (ws_size < WS_NEEDED) return;

  float* c = (float*)(ws + OFF_C);
  float* xpre = (float*)(ws + OFF_XPRE);
  ushort_t* qb = (ushort_t*)(ws + OFF_Q);
  ushort_t* kb = (ushort_t*)(ws + OFF_K);
  ushort_t* vb = (ushort_t*)(ws + OFF_V);
  ushort_t* attnb = (ushort_t*)(ws + OFF_ATTN);
  ushort_t* evb = (ushort_t*)(ws + OFF_EV);
  float* sbuf = (float*)(ws + OFF_SBUF);
  float* hbuf = (float*)(ws + OFF_H);
  ushort_t* logb = (ushort_t*)(ws + OFF_LOG);
  int* deg = (int*)(ws + OFF_DEG);
  int* row_ptr = (int*)(ws + OFF_ROWPTR);
  int* wptr = (int*)(ws + OFF_WPTR);
  int* csr_e = (int*)(ws + OFF_CSRE);
  int* csr_src = (int*)(ws + OFF_CSRSRC);
  float* meancut = (float*)(ws + OFF_MEANCUT);

  // CSR build
  hipMemsetAsync(ws + OFF_DEG, 0, 24000, stream);
  k_hist<<<282, 256, 0, stream>>>(dst_idx, deg);
  k_scan<<<1, 1024, 0, stream>>>(deg, row_ptr, wptr);
  k_scatter<<<282, 256, 0, stream>>>(src_idx, dst_idx, wptr, csr_e, csr_src);

  k_ln_t<<<1500, 256, 0, stream>>>(f_time, ln_s, ln_b, sbuf);
  k_cond_mm<<<750, 256, 0, stream>>>(sbuf, W_c, b_c, c);
  k_lnmod<<<3000, 256, 0, stream>>>(f_nodes, c, xpre, 0, 384);

  dim3 g94(94, 18);
  k_rowmat<<<g94, 256, 0, stream>>>(xpre, Wq, qb);
  k_rowmat<<<g94, 256, 0, stream>>>(xpre, Wk, kb);
  k_rowmat<<<g94, 256, 0, stream>>>(xpre, Wv, vb);

  k_edge<<<2048, 256, 0, stream>>>(f_edges, We_qk, We_v, qb, kb, src_idx, dst_idx,
                                   evb, logb);
  k_attnB<<<NN, 256, 0, stream>>>(evb, vb, logb, cutoff, row_ptr, csr_e, csr_src,
                                  attnb, meancut);
  k_wo_post<<<g94, 256, 0, stream>>>(attnb, Wo, xpre, f_nodes, c, meancut, out);

  k_lnmod<<<3000, 256, 0, stream>>>(out, c, xpre, 832, 1216);  // x_pre2
  k_mlp1<<<750, 256, 0, stream>>>(xpre, W1, hbuf);
  k_mlp2<<<750, 256, 0, stream>>>(hbuf, W2, c, out);
}

// Round 4
// 1587.170 us; speedup vs baseline: 1.0436x; 1.0436x over previous
//
#include <hip/hip_runtime.h>
#include <math.h>

// SO3 DiT layer, MI355X.
// Round 4: (a) k_edge via wave-uniform s_load fe rows (batched drains) + 4-way
// accumulator ILP; (b) mlp1/mlp2/cond_mm broadcast activations laundered into
// per-lane VMEM (defeats uniform->s_load lowering whose out-of-order returns
// force serializing lgkmcnt(0) drains).

#define NN 6000
#define EE 72000

typedef unsigned short ushort_t;

__device__ __forceinline__ float wsum(float v) {
#pragma unroll
  for (int o = 32; o >= 1; o >>= 1) v += __shfl_xor(v, o, 64);
  return v;
}
__device__ __forceinline__ int deg_of(int m) { return (m == 0) ? 0 : ((m < 4) ? 1 : 2); }
__device__ __forceinline__ ushort_t f2b(float x) {
  unsigned u = __float_as_uint(x);
  unsigned r = ((u >> 16) & 1u) + 0x7fffu;
  return (ushort_t)((u + r) >> 16);
}
__device__ __forceinline__ float b2f(ushort_t h) {
  return __uint_as_float(((unsigned)h) << 16);
}
// 0 in a VGPR the compiler cannot constant-fold: keeps derived addresses
// divergent -> global_load (VMEM, pipelined vmcnt) instead of s_load (SMEM,
// out-of-order, full lgkmcnt(0) drain per use).
__device__ __forceinline__ int vgpr_zero() {
  return __shfl((int)(threadIdx.x >> 8), 0);  // 0 for blockDim<=256, opaque
}

// ---------------- K1a: LayerNorm(T=64) + SiLU, one wave per node ----------------
__global__ __launch_bounds__(256) void k_ln_t(const float* __restrict__ ft,
                                              const float* __restrict__ lns,
                                              const float* __restrict__ lnb,
                                              float* __restrict__ sbuf) {
  int w = (blockIdx.x * 256 + threadIdx.x) >> 6;
  int lane = threadIdx.x & 63;
  float t = ft[(size_t)w * 64 + lane];
  float mu = wsum(t) * (1.f / 64.f);
  float d = t - mu;
  float var = wsum(d * d) * (1.f / 64.f);
  float cin = d * rsqrtf(var + 1e-6f) * lns[lane] + lnb[lane];
  sbuf[(size_t)w * 64 + lane] = cin / (1.f + expf(-cin));
}

// ---------------- K1b: c = silu @ W_c + b_c  (64 -> 1664), 8 nodes/block ----------------
__global__ __launch_bounds__(256) void k_cond_mm(const float* __restrict__ sbuf,
                                                 const float* __restrict__ Wc,
                                                 const float* __restrict__ bc,
                                                 float* __restrict__ c) {
  int n0 = blockIdx.x * 8;  // 750 blocks
  const float* sz = sbuf + vgpr_zero() + (size_t)n0 * 64;
  for (int jj = threadIdx.x; jj < 1664; jj += 256) {
    float acc[8] = {0, 0, 0, 0, 0, 0, 0, 0};
#pragma unroll
    for (int t = 0; t < 16; t++) {
      float w0 = Wc[(size_t)(4 * t + 0) * 1664 + jj];
      float w1 = Wc[(size_t)(4 * t + 1) * 1664 + jj];
      float w2 = Wc[(size_t)(4 * t + 2) * 1664 + jj];
      float w3 = Wc[(size_t)(4 * t + 3) * 1664 + jj];
#pragma unroll
      for (int nd = 0; nd < 8; nd++) {
        float4 sv = *(const float4*)(sz + (size_t)nd * 64 + 4 * t);
        acc[nd] += sv.x * w0 + sv.y * w1 + sv.z * w2 + sv.w * w3;
      }
    }
    float b = bc[jj];
#pragma unroll
    for (int nd = 0; nd < 8; nd++) c[(size_t)(n0 + nd) * 1664 + jj] = acc[nd] + b;
  }
}

// ---------------- K2/K8: eqv layernorm + modulate, one wave per (n,p) ----------------
__global__ __launch_bounds__(256) void k_lnmod(const float* __restrict__ xin,
                                               const float* __restrict__ c,
                                               float* __restrict__ xout,
                                               int goff, int boff) {
  int w = (blockIdx.x * 256 + threadIdx.x) >> 6;
  int lane = threadIdx.x & 63;
  int n = w >> 1, p = w & 1;
  const float* xb = xin + (size_t)w * 576 + lane;
  float x0 = xb[0], x1 = xb[64], x2 = xb[128], x3 = xb[192], x4 = xb[256];
  float x5 = xb[320], x6 = xb[384], x7 = xb[448], x8 = xb[512];
  float mu = wsum(x0) * (1.f / 64.f);
  x0 -= mu;
  float n20 = x0 * x0;
  float n21 = (x1 * x1 + x2 * x2 + x3 * x3) * (1.f / 3.f);
  float n22 = (x4 * x4 + x5 * x5 + x6 * x6 + x7 * x7 + x8 * x8) * (1.f / 5.f);
  n20 = wsum(n20) * (1.f / 64.f);
  n21 = wsum(n21) * (1.f / 64.f);
  n22 = wsum(n22) * (1.f / 64.f);
  float i0 = rsqrtf(n20 + 1e-6f), i1 = rsqrtf(n21 + 1e-6f), i2 = rsqrtf(n22 + 1e-6f);
  const float* cb = c + (size_t)n * 1664;
  float g0 = 1.f + cb[goff + p * 192 + lane];
  float g1 = 1.f + cb[goff + p * 192 + 64 + lane];
  float g2 = 1.f + cb[goff + p * 192 + 128 + lane];
  float bsh = cb[boff + lane];
  float* ob = xout + (size_t)w * 576 + lane;
  ob[0] = x0 * i0 * g0 + bsh;
  ob[64] = x1 * i1 * g1;
  ob[128] = x2 * i1 * g1;
  ob[192] = x3 * i1 * g1;
  ob[256] = x4 * i2 * g2;
  ob[320] = x5 * i2 * g2;
  ob[384] = x6 * i2 * g2;
  ob[448] = x7 * i2 * g2;
  ob[512] = x8 * i2 * g2;
}

// ---------------- K3: per-(p,m) 64x64 projection -> bf16 out ----------------
__global__ __launch_bounds__(256) void k_rowmat(const float* __restrict__ x,
                                                const float* __restrict__ W,
                                                ushort_t* __restrict__ outb) {
  int pm = blockIdx.y;
  int p = pm / 9, mm = pm % 9, dm = deg_of(mm);
  int lane = threadIdx.x & 63;
  const float* Wb = W + (size_t)(p * 3 + dm) * 4096;
  float wreg[64];
#pragma unroll
  for (int f = 0; f < 64; f++) wreg[f] = Wb[f * 64 + lane];
  int wid = (blockIdx.x * 256 + threadIdx.x) >> 6;
  int nwaves = (gridDim.x * 256) >> 6;
  for (int n = wid; n < NN; n += nwaves) {
    const float4* xr4 = (const float4*)(x + ((size_t)n * 18 + pm) * 64);
    float a0 = 0.f, a1 = 0.f, a2 = 0.f, a3 = 0.f;
#pragma unroll
    for (int t = 0; t < 16; t++) {
      float4 xv = xr4[t];
      a0 += xv.x * wreg[4 * t];
      a1 += xv.y * wreg[4 * t + 1];
      a2 += xv.z * wreg[4 * t + 2];
      a3 += xv.w * wreg[4 * t + 3];
    }
    outb[((size_t)n * 18 + pm) * 64 + lane] = f2b((a0 + a1) + (a2 + a3));
  }
}

// ---------------- CSR build: histogram -> scan -> scatter ----------------
__global__ __launch_bounds__(256) void k_hist(const int* __restrict__ dst_idx,
                                              int* __restrict__ deg) {
  int e = blockIdx.x * 256 + threadIdx.x;
  if (e < EE) atomicAdd(deg + dst_idx[e], 1);
}

__global__ __launch_bounds__(1024) void k_scan(const int* __restrict__ deg,
                                               int* __restrict__ row_ptr,
                                               int* __restrict__ wptr) {
  __shared__ int part[1024];
  int t = threadIdx.x;
  int base = t * 6;
  int loc[6];
  int s = 0;
#pragma unroll
  for (int i = 0; i < 6; i++) {
    int idx = base + i;
    int d = (idx < NN) ? deg[idx] : 0;
    loc[i] = s;
    s += d;
  }
  part[t] = s;
  __syncthreads();
  int val = s;
  for (int off = 1; off < 1024; off <<= 1) {
    int tmp = (t >= off) ? part[t - off] : 0;
    __syncthreads();
    part[t] += tmp;
    __syncthreads();
  }
  int excl = part[t] - val;
#pragma unroll
  for (int i = 0; i < 6; i++) {
    int idx = base + i;
    if (idx < NN) {
      int v = excl + loc[i];
      row_ptr[idx] = v;
      wptr[idx] = v;
    }
  }
  if (t == 1023) row_ptr[NN] = excl + val;
}

__global__ __launch_bounds__(256) void k_scatter(const int* __restrict__ src_idx,
                                                 const int* __restrict__ dst_idx,
                                                 int* __restrict__ wptr,
                                                 int* __restrict__ csr_e,
                                                 int* __restrict__ csr_src) {
  int e = blockIdx.x * 256 + threadIdx.x;
  if (e < EE) {
    int d = dst_idx[e];
    int pos = atomicAdd(wptr + d, 1);
    csr_e[pos] = e;
    csr_src[pos] = src_idx[e];
  }
}

// ---------------- Pass A: edge-streaming eq/ev GEMM + logits ----------------
// Wave per edge; e/s/d forced wave-uniform so fe rows go through batched
// s_load (scalar pipe, one drain per row amortized over 128 FMA); 4-way
// accumulator ILP per dot product.
__global__ __launch_bounds__(256) void k_edge(const float* __restrict__ fe,
                                              const float* __restrict__ Weqk,
                                              const float* __restrict__ Wev,
                                              const ushort_t* __restrict__ qb,
                                              const ushort_t* __restrict__ kb,
                                              const int* __restrict__ src_idx,
                                              const int* __restrict__ dst_idx,
                                              ushort_t* __restrict__ evb,
                                              ushort_t* __restrict__ logb) {
  int lane = threadIdx.x & 63;
  float wqk[64], wev[64];
#pragma unroll
  for (int f = 0; f < 64; f++) {
    wqk[f] = Weqk[f * 64 + lane];
    wev[f] = Wev[f * 64 + lane];
  }
  int wid = (blockIdx.x * 256 + threadIdx.x) >> 6;
  int nw = (gridDim.x * 256) >> 6;
  for (int ee = wid; ee < EE; ee += nw) {
    int e = __builtin_amdgcn_readfirstlane(ee);
    int s = __builtin_amdgcn_readfirstlane(src_idx[e]);
    int d = __builtin_amdgcn_readfirstlane(dst_idx[e]);
    const float* feb = fe + (size_t)e * 576;  // uniform -> batched s_load
    const ushort_t* qr = qb + (size_t)d * 1152 + lane;
    const ushort_t* kr = kb + (size_t)s * 1152 + lane;
    ushort_t* evr = evb + (size_t)e * 576 + lane;
    float lacc = 0.f;
    for (int m = 0; m < 9; m++) {
      float eq0 = 0.f, eq1 = 0.f, eq2 = 0.f, eq3 = 0.f;
      float ev0 = 0.f, ev1 = 0.f, ev2 = 0.f, ev3 = 0.f;
#pragma unroll
      for (int t = 0; t < 16; t++) {
        float a0 = feb[m * 64 + 4 * t + 0];
        float a1 = feb[m * 64 + 4 * t + 1];
        float a2 = feb[m * 64 + 4 * t + 2];
        float a3 = feb[m * 64 + 4 * t + 3];
        eq0 += a0 * wqk[4 * t + 0];
        ev0 += a0 * wev[4 * t + 0];
        eq1 += a1 * wqk[4 * t + 1];
        ev1 += a1 * wev[4 * t + 1];
        eq2 += a2 * wqk[4 * t + 2];
        ev2 += a2 * wev[4 * t + 2];
        eq3 += a3 * wqk[4 * t + 3];
        ev3 += a3 * wev[4 * t + 3];
      }
      float eq = (eq0 + eq1) + (eq2 + eq3);
      float ev = (ev0 + ev1) + (ev2 + ev3);
      evr[m * 64] = f2b(ev);
      float q0 = b2f(qr[m * 64]), q1 = b2f(qr[m * 64 + 576]);
      float k0 = b2f(kr[m * 64]), k1 = b2f(kr[m * 64 + 576]);
      lacc += eq * (q0 * k0 + q1 * k1);
    }
    lacc *= 0.05892556509887896f;  // 1/sqrt(288)
    lacc += __shfl_xor(lacc, 8, 64);
    lacc += __shfl_xor(lacc, 4, 64);
    lacc += __shfl_xor(lacc, 2, 64);
    lacc += __shfl_xor(lacc, 1, 64);
    if ((lane & 15) == 0) logb[(size_t)e * 4 + (lane >> 4)] = f2b(lacc);
  }
}

// ---------------- Pass B: block-per-dst gather, online softmax, LDS merge ----------------
__global__ __launch_bounds__(256) void k_attnB(const ushort_t* __restrict__ evb,
                                               const ushort_t* __restrict__ vb,
                                               const ushort_t* __restrict__ logb,
                                               const float* __restrict__ cutoff,
                                               const int* __restrict__ row_ptr,
                                               const int* __restrict__ csr_e,
                                               const int* __restrict__ csr_src,
                                               ushort_t* __restrict__ attnb,
                                               float* __restrict__ meancut) {
  __shared__ float st[4][64][21];
  int d = blockIdx.x;
  int w = threadIdx.x >> 6, lane = threadIdx.x & 63;
  int beg = row_ptr[d], end = row_ptr[d + 1];
  float ml = -3.0e38f, dl = 0.f, cs = 0.f;
  float acc[18];
#pragma unroll
  for (int j = 0; j < 18; j++) acc[j] = 0.f;
  for (int i = beg + w; i < end; i += 4) {
    int e = csr_e[i];
    int s = csr_src[i];
    float lg = b2f(logb[(size_t)e * 4 + (lane >> 4)]);
    float co = cutoff[e];
    cs += co;
    float mnew = fmaxf(ml, lg);
    float sc = expf(ml - mnew);
    float wv = expf(lg - mnew) * co;
    dl = dl * sc + wv;
    const ushort_t* evr = evb + (size_t)e * 576 + lane;
    const ushort_t* vr = vb + (size_t)s * 1152 + lane;
#pragma unroll
    for (int m = 0; m < 9; m++) {
      float sv = wv * b2f(evr[m * 64]);
      acc[m] = acc[m] * sc + sv * b2f(vr[m * 64]);
      acc[m + 9] = acc[m + 9] * sc + sv * b2f(vr[m * 64 + 576]);
    }
    ml = mnew;
  }
  st[w][lane][0] = ml;
  st[w][lane][1] = dl;
  st[w][lane][2] = cs;
#pragma unroll
  for (int j = 0; j < 18; j++) st[w][lane][3 + j] = acc[j];
  __syncthreads();
  if (threadIdx.x < 64) {
    float M = st[0][lane][0];
#pragma unroll
    for (int w2 = 1; w2 < 4; w2++) M = fmaxf(M, st[w2][lane][0]);
    float D = 0.f, CS = 0.f;
    float A[18];
#pragma unroll
    for (int j = 0; j < 18; j++) A[j] = 0.f;
#pragma unroll
    for (int w2 = 0; w2 < 4; w2++) {
      float sc = expf(st[w2][lane][0] - M);
      D += st[w2][lane][1] * sc;
      CS += st[w2][lane][2];
#pragma unroll
      for (int j = 0; j < 18; j++) A[j] += st[w2][lane][3 + j] * sc;
    }
    float inv = 1.f / (D + 1e-9f);
    ushort_t* ob = attnb + (size_t)d * 1152 + lane;
#pragma unroll
    for (int m = 0; m < 9; m++) {
      ob[m * 64] = f2b(A[m] * inv);
      ob[m * 64 + 576] = f2b(A[m + 9] * inv);
    }
    if (lane == 0) meancut[d] = CS / fmaxf((float)(end - beg), 1.f);
  }
}

// ---------------- K7: Wo projection + post-select + gate(a1) + residual ----------------
__global__ __launch_bounds__(256) void k_wo_post(const ushort_t* __restrict__ attnb,
                                                 const float* __restrict__ Wo,
                                                 const float* __restrict__ xpre,
                                                 const float* __restrict__ fnodes,
                                                 const float* __restrict__ c,
                                                 const float* __restrict__ meancut,
                                                 float* __restrict__ out) {
  int pm = blockIdx.y;
  int p = pm / 9, mm = pm % 9, dm = deg_of(mm);
  int lane = threadIdx.x & 63;
  const float* Wb = Wo + (size_t)(p * 3 + dm) * 4096;
  float wreg[64];
#pragma unroll
  for (int f = 0; f < 64; f++) wreg[f] = Wb[f * 64 + lane];
  int wid = (blockIdx.x * 256 + threadIdx.x) >> 6;
  int nwaves = (gridDim.x * 256) >> 6;
  for (int n = wid; n < NN; n += nwaves) {
    const uint4* xr4 = (const uint4*)(attnb + ((size_t)n * 18 + pm) * 64);
    float acc = 0.f;
#pragma unroll
    for (int t = 0; t < 8; t++) {
      uint4 u = xr4[t];
      acc += __uint_as_float(u.x << 16) * wreg[8 * t + 0];
      acc += __uint_as_float(u.x & 0xffff0000u) * wreg[8 * t + 1];
      acc += __uint_as_float(u.y << 16) * wreg[8 * t + 2];
      acc += __uint_as_float(u.y & 0xffff0000u) * wreg[8 * t + 3];
      acc += __uint_as_float(u.z << 16) * wreg[8 * t + 4];
      acc += __uint_as_float(u.z & 0xffff0000u) * wreg[8 * t + 5];
      acc += __uint_as_float(u.w << 16) * wreg[8 * t + 6];
      acc += __uint_as_float(u.w & 0xffff0000u) * wreg[8 * t + 7];
    }
    float mc = meancut[n];
    size_t idx = ((size_t)n * 18 + pm) * 64 + lane;
    float post = (mc < 1e-5f) ? xpre[idx] : acc;
    float a1v = c[(size_t)n * 1664 + 448 + (p * 3 + dm) * 64 + lane];
    out[idx] = fnodes[idx] + a1v * post;
  }
}

// ---------------- K9a: h = eqv_gelu(x_pre2 @ W1), 8 nodes/block ----------------
__global__ __launch_bounds__(256) void k_mlp1(const float* __restrict__ xp2,
                                              const float* __restrict__ W1,
                                              float* __restrict__ h) {
  int n0 = blockIdx.x * 8;  // 750 blocks
  int j = threadIdx.x;
  const float* xz = xp2 + vgpr_zero() + (size_t)n0 * 1152;
  float gate[8];
  {
    float acc[8] = {0, 0, 0, 0, 0, 0, 0, 0};
#pragma unroll
    for (int t = 0; t < 16; t++) {
      float w0 = W1[(size_t)(4 * t + 0) * 256 + j];
      float w1 = W1[(size_t)(4 * t + 1) * 256 + j];
      float w2 = W1[(size_t)(4 * t + 2) * 256 + j];
      float w3 = W1[(size_t)(4 * t + 3) * 256 + j];
#pragma unroll
      for (int nd = 0; nd < 8; nd++) {
        float4 xv = *(const float4*)(xz + (size_t)nd * 1152 + 4 * t);
        acc[nd] += xv.x * w0 + xv.y * w1 + xv.z * w2 + xv.w * w3;
      }
    }
#pragma unroll
    for (int nd = 0; nd < 8; nd++) {
      float s = acc[nd];
      float g = (fabsf(s) > 1e-4f)
                    ? 0.5f * (1.f + tanhf(0.7978845608028654f * (s + 0.044715f * s * s * s)))
                    : 0.5f;
      gate[nd] = g;
      h[(size_t)(n0 + nd) * 4608 + j] = s * g;
    }
  }
  for (int pm = 1; pm < 18; pm++) {
    int p = pm / 9, mm = pm % 9, dm = deg_of(mm);
    const float* wb = W1 + (size_t)(p * 3 + dm) * 16384;
    float acc[8] = {0, 0, 0, 0, 0, 0, 0, 0};
#pragma unroll
    for (int t = 0; t < 16; t++) {
      float w0 = wb[(size_t)(4 * t + 0) * 256 + j];
      float w1 = wb[(size_t)(4 * t + 1) * 256 + j];
      float w2 = wb[(size_t)(4 * t + 2) * 256 + j];
      float w3 = wb[(size_t)(4 * t + 3) * 256 + j];
#pragma unroll
      for (int nd = 0; nd < 8; nd++) {
        float4 xv = *(const float4*)(xz + (size_t)nd * 1152 + pm * 64 + 4 * t);
        acc[nd] += xv.x * w0 + xv.y * w1 + xv.z * w2 + xv.w * w3;
      }
    }
#pragma unroll
    for (int nd = 0; nd < 8; nd++)
      h[(size_t)(n0 + nd) * 4608 + pm * 256 + j] = acc[nd] * gate[nd];
  }
}

// ---------------- K9b: out += a2 * (h @ W2), 8 nodes/block ----------------
__global__ __launch_bounds__(256) void k_mlp2(const float* __restrict__ h,
                                              const float* __restrict__ W2,
                                              const float* __restrict__ c,
                                              float* __restrict__ out) {
  int n0 = blockIdx.x * 8;  // 750 blocks
  int g = threadIdx.x & 63;
  int pr = threadIdx.x >> 6;
  const float* hz = h + vgpr_zero() + (size_t)n0 * 4608;
  for (int pm = pr; pm < 18; pm += 4) {
    int p = pm / 9, mm = pm % 9, dm = deg_of(mm);
    const float* wb = W2 + (size_t)(p * 3 + dm) * 16384;
    float acc[8] = {0, 0, 0, 0, 0, 0, 0, 0};
#pragma unroll 16
    for (int t = 0; t < 64; t++) {
      float w0 = wb[(size_t)(4 * t + 0) * 64 + g];
      float w1 = wb[(size_t)(4 * t + 1) * 64 + g];
      float w2 = wb[(size_t)(4 * t + 2) * 64 + g];
      float w3 = wb[(size_t)(4 * t + 3) * 64 + g];
#pragma unroll
      for (int nd = 0; nd < 8; nd++) {
        float4 hv = *(const float4*)(hz + (size_t)nd * 4608 + pm * 256 + 4 * t);
        acc[nd] += hv.x * w0 + hv.y * w1 + hv.z * w2 + hv.w * w3;
      }
    }
#pragma unroll
    for (int nd = 0; nd < 8; nd++) {
      int n = n0 + nd;
      size_t idx = ((size_t)n * 18 + pm) * 64 + g;
      out[idx] += c[(size_t)n * 1664 + 1280 + (p * 3 + dm) * 64 + g] * acc[nd];
    }
  }
}

// ---------------- workspace layout (bytes) ----------------
#define OFF_C 0UL              // f32 39,936,000
#define OFF_XPRE 39936000UL    // f32 27,648,000 (x_pre then x_pre2)
#define OFF_Q 67584000UL       // bf16 13,824,000
#define OFF_K 81408000UL       // bf16 13,824,000
#define OFF_V 95232000UL       // bf16 13,824,000
#define OFF_ATTN 109056000UL   // bf16 13,824,000
#define OFF_EV 122880000UL     // bf16 82,944,000 -> 205,824,000
#define OFF_SBUF 122880000UL   // f32 1,536,000 (overlays EV; dead before Pass A)
#define OFF_H 67584000UL       // f32 110,592,000 (overlays Q..EV head; after wo_post)
#define OFF_LOG 205824000UL    // bf16 576,000
#define OFF_DEG 206400000UL    // 24,000
#define OFF_ROWPTR 206424000UL // 24,032 (incl pad)
#define OFF_WPTR 206448032UL   // 24,000
#define OFF_CSRE 206472032UL   // 288,000
#define OFF_CSRSRC 206760032UL // 288,000
#define OFF_MEANCUT 207048032UL// 24,000
#define WS_NEEDED 207072032UL

extern "C" void kernel_launch(void* const* d_in, const int* in_sizes, int n_in,
                              void* d_out, int out_size, void* d_ws, size_t ws_size,
                              hipStream_t stream) {
  const float* f_nodes = (const float*)d_in[0];
  const float* f_edges = (const float*)d_in[1];
  const float* f_time = (const float*)d_in[2];
  const float* cutoff = (const float*)d_in[3];
  const float* ln_s = (const float*)d_in[4];
  const float* ln_b = (const float*)d_in[5];
  const float* W_c = (const float*)d_in[6];
  const float* b_c = (const float*)d_in[7];
  const float* Wq = (const float*)d_in[8];
  const float* Wk = (const float*)d_in[9];
  const float* Wv = (const float*)d_in[10];
  const float* Wo = (const float*)d_in[11];
  const float* We_qk = (const float*)d_in[12];
  const float* We_v = (const float*)d_in[13];
  const float* W1 = (const float*)d_in[14];
  const float* W2 = (const float*)d_in[15];
  const int* src_idx = (const int*)d_in[16];
  const int* dst_idx = (const int*)d_in[17];
  float* out = (float*)d_out;
  char* ws = (char*)d_ws;
  if (ws_size < WS_NEEDED) return;

  float* c = (float*)(ws + OFF_C);
  float* xpre = (float*)(ws + OFF_XPRE);
  ushort_t* qb = (ushort_t*)(ws + OFF_Q);
  ushort_t* kb = (ushort_t*)(ws + OFF_K);
  ushort_t* vb = (ushort_t*)(ws + OFF_V);
  ushort_t* attnb = (ushort_t*)(ws + OFF_ATTN);
  ushort_t* evb = (ushort_t*)(ws + OFF_EV);
  float* sbuf = (float*)(ws + OFF_SBUF);
  float* hbuf = (float*)(ws + OFF_H);
  ushort_t* logb = (ushort_t*)(ws + OFF_LOG);
  int* deg = (int*)(ws + OFF_DEG);
  int* row_ptr = (int*)(ws + OFF_ROWPTR);
  int* wptr = (int*)(ws + OFF_WPTR);
  int* csr_e = (int*)(ws + OFF_CSRE);
  int* csr_src = (int*)(ws + OFF_CSRSRC);
  float* meancut = (float*)(ws + OFF_MEANCUT);

  // CSR build
  hipMemsetAsync(ws + OFF_DEG, 0, 24000, stream);
  k_hist<<<282, 256, 0, stream>>>(dst_idx, deg);
  k_scan<<<1, 1024, 0, stream>>>(deg, row_ptr, wptr);
  k_scatter<<<282, 256, 0, stream>>>(src_idx, dst_idx, wptr, csr_e, csr_src);

  k_ln_t<<<1500, 256, 0, stream>>>(f_time, ln_s, ln_b, sbuf);
  k_cond_mm<<<750, 256, 0, stream>>>(sbuf, W_c, b_c, c);
  k_lnmod<<<3000, 256, 0, stream>>>(f_nodes, c, xpre, 0, 384);

  dim3 g94(94, 18);
  k_rowmat<<<g94, 256, 0, stream>>>(xpre, Wq, qb);
  k_rowmat<<<g94, 256, 0, stream>>>(xpre, Wk, kb);
  k_rowmat<<<g94, 256, 0, stream>>>(xpre, Wv, vb);

  k_edge<<<2048, 256, 0, stream>>>(f_edges, We_qk, We_v, qb, kb, src_idx, dst_idx,
                                   evb, logb);
  k_attnB<<<NN, 256, 0, stream>>>(evb, vb, logb, cutoff, row_ptr, csr_e, csr_src,
                                  attnb, meancut);
  k_wo_post<<<g94, 256, 0, stream>>>(attnb, Wo, xpre, f_nodes, c, meancut, out);

  k_lnmod<<<3000, 256, 0, stream>>>(out, c, xpre, 832, 1216);  // x_pre2
  k_mlp1<<<750, 256, 0, stream>>>(xpre, W1, hbuf);
  k_mlp2<<<750, 256, 0, stream>>>(hbuf, W2, c, out);
}